// Round 1
// baseline (103.473 us; speedup 1.0000x reference)
//
#include <hip/hip_runtime.h>
#include <math.h>

#define D 8192
#define B 8
#define E 131072
#define HID 256
#define TDIM 128

// ws layout (float offsets)
//  xT : [D*B]     @ 0        x transposed to [n][b]
//  dd : [D*B]     @ 65536    L_down x
//  uu : [D*B]     @ 131072   L_up x
//  hb : [D*B]     @ 196608
//  hc : [D*B]     @ 262144
//  y  : [D*B]     @ 327680   SNN output (x_out transposed)
//  g  : [B*HID]   @ 393216   map_b + t_out  (+= y @ map_w)
//  s  : [B*HID]   @ 395264   silu layer output
//  sc : [16]      @ 397312   9 collapsed scalars
#define OFF_XT 0
#define OFF_DD 65536
#define OFF_UU 131072
#define OFF_HB 196608
#define OFF_HC 262144
#define OFF_Y  327680
#define OFF_G  393216
#define OFF_S  395264
#define OFF_SC 397312

__global__ void k_prep(const float* __restrict__ x, const float* __restrict__ t,
                       const float* __restrict__ W1, const float* __restrict__ W2,
                       const float* __restrict__ t_w1, const float* __restrict__ t_b1,
                       const float* __restrict__ t_w2, const float* __restrict__ t_b2,
                       const float* __restrict__ map_b, const float* __restrict__ o_b2,
                       float* __restrict__ ws, float* __restrict__ out)
{
    const int blk = blockIdx.x, tid = threadIdx.x;
    if (blk == 0) {
        // 9 collapsed scalars: sc[j*3+k] = sum_i W1[0,i,k] * W2[i,0,j]
        __shared__ float red[256];
        float w1k[3], w2j[3];
        #pragma unroll
        for (int k = 0; k < 3; k++) w1k[k] = W1[tid * 3 + k];
        #pragma unroll
        for (int j = 0; j < 3; j++) w2j[j] = W2[tid * 3 + j];
        float* sc = ws + OFF_SC;
        for (int j = 0; j < 3; j++)
            for (int k = 0; k < 3; k++) {
                red[tid] = w1k[k] * w2j[j];
                __syncthreads();
                for (int off = 128; off > 0; off >>= 1) {
                    if (tid < off) red[tid] += red[tid + off];
                    __syncthreads();
                }
                if (tid == 0) sc[j * 3 + k] = red[0];
                __syncthreads();
            }
    } else if (blk == 1) {
        // time-embedding MLP for all 8 batches; g = map_b + t_out
        __shared__ float emb[TDIM];
        __shared__ float h1[HID];
        float* g = ws + OFF_G;
        for (int b = 0; b < B; b++) {
            float tb = t[b];
            if (tid < TDIM) {
                int j = tid & 63;
                float freq = expf(-0.14391156831212787f * (float)j); // ln(10000)/64
                float a = tb * freq;
                emb[tid] = (tid < 64) ? cosf(a) : sinf(a);
            }
            __syncthreads();
            float z = t_b1[tid];
            for (int i = 0; i < TDIM; i++) z += emb[i] * t_w1[i * HID + tid];
            h1[tid] = z / (1.f + expf(-z));
            __syncthreads();
            float z2 = t_b2[tid];
            for (int i = 0; i < HID; i++) z2 += h1[i] * t_w2[i * HID + tid];
            g[b * HID + tid] = map_b[tid] + z2;
            __syncthreads();
        }
    } else {
        // blocks 2..257: transpose x, zero dd/uu, init out with o_b2
        int idx = (blk - 2) * 256 + tid;          // 0..65535
        int b = idx & 7, n = idx >> 3;
        ws[OFF_XT + idx] = x[b * D + n];
        ws[OFF_DD + idx] = 0.f;
        ws[OFF_UU + idx] = 0.f;
        out[idx] = o_b2[idx & (D - 1)];           // idx = b*D + n
    }
}

// COO scatter: dst[row,b] += v * src[col,b] for both Laplacians.
// pass1: src_d=src_u=xT, dst_d=dd, dst_u=uu.  pass2: src_d=hb, src_u=hc, dst_d=dst_u=y.
__global__ void k_scatter(const int* __restrict__ ldi, const float* __restrict__ ldv,
                          const int* __restrict__ lui, const float* __restrict__ luv,
                          const float* __restrict__ src_d, const float* __restrict__ src_u,
                          float* __restrict__ dst_d, float* __restrict__ dst_u)
{
    int gtid = blockIdx.x * 256 + threadIdx.x;    // 0 .. 2*E*8-1
    int b = gtid & 7;
    int e = gtid >> 3;
    const int* idx; const float* val; const float* src; float* dst;
    if (e < E) { idx = ldi; val = ldv; src = src_d; dst = dst_d; }
    else       { e -= E; idx = lui; val = luv; src = src_u; dst = dst_u; }
    int row = idx[e];
    int col = idx[E + e];
    float v = val[e];
    atomicAdd(&dst[row * 8 + b], v * src[col * 8 + b]);
}

__global__ void k_mid(float* __restrict__ ws)
{
    int idx = blockIdx.x * 256 + threadIdx.x;     // 0..65535
    const float* sc = ws + OFF_SC;
    float xv = ws[OFF_XT + idx];
    float dv = ws[OFF_DD + idx];
    float uv = ws[OFF_UU + idx];
    ws[OFF_Y  + idx] = sc[0] * xv + sc[1] * dv + sc[2] * uv;
    ws[OFF_HB + idx] = sc[3] * xv + sc[4] * dv + sc[5] * uv;
    ws[OFF_HC + idx] = sc[6] * xv + sc[7] * dv + sc[8] * uv;
}

// g[b,j] += sum_n y[n,b] * map_w[n,j]   (64 blocks x 128 rows each)
__global__ void k_map(const float* __restrict__ map_w, float* __restrict__ ws)
{
    __shared__ float ysl[128 * 8];
    int blk = blockIdx.x, tid = threadIdx.x;
    const float* y = ws + OFF_Y;
    float* g = ws + OFF_G;
    int base = blk * 128 * 8;
    for (int i = tid; i < 1024; i += 256) ysl[i] = y[base + i];
    __syncthreads();
    float acc[8] = {0.f, 0.f, 0.f, 0.f, 0.f, 0.f, 0.f, 0.f};
    int nbase = blk * 128;
    for (int r = 0; r < 128; r++) {
        float w = map_w[(nbase + r) * HID + tid];
        #pragma unroll
        for (int b = 0; b < 8; b++) acc[b] += ysl[r * 8 + b] * w;
    }
    #pragma unroll
    for (int b = 0; b < 8; b++) atomicAdd(&g[b * HID + tid], acc[b]);
}

// s[b,j] = silu(sum_i g[b,i]*o_w1[i,j] + o_b1[j])   (8 blocks, one per batch)
__global__ void k_mlp(const float* __restrict__ o_w1, const float* __restrict__ o_b1,
                      float* __restrict__ ws)
{
    __shared__ float gs[HID];
    int b = blockIdx.x, tid = threadIdx.x;
    const float* g = ws + OFF_G;
    float* s = ws + OFF_S;
    gs[tid] = g[b * HID + tid];
    __syncthreads();
    float z = o_b1[tid];
    for (int i = 0; i < HID; i++) z += gs[i] * o_w1[i * HID + tid];
    s[b * HID + tid] = z / (1.f + expf(-z));
}

// out[b,n] += sum_j s[b,j]*o_w2[j,n]   (grid 32 n-chunks x 4 j-chunks)
__global__ void k_out(const float* __restrict__ o_w2, const float* __restrict__ ws,
                      float* __restrict__ out)
{
    __shared__ float ssl[8 * 64];
    int nc = blockIdx.x, jc = blockIdx.y, tid = threadIdx.x;
    const float* s = ws + OFF_S;
    for (int i = tid; i < 512; i += 256) {
        int b = i >> 6, jj = i & 63;
        ssl[i] = s[b * HID + jc * 64 + jj];
    }
    __syncthreads();
    int n = nc * 256 + tid;
    float acc[8] = {0.f, 0.f, 0.f, 0.f, 0.f, 0.f, 0.f, 0.f};
    for (int jj = 0; jj < 64; jj++) {
        int j = jc * 64 + jj;
        float w = o_w2[j * D + n];
        #pragma unroll
        for (int b = 0; b < 8; b++) acc[b] += ssl[b * 64 + jj] * w;
    }
    #pragma unroll
    for (int b = 0; b < 8; b++) atomicAdd(&out[b * D + n], acc[b]);
}

extern "C" void kernel_launch(void* const* d_in, const int* in_sizes, int n_in,
                              void* d_out, int out_size, void* d_ws, size_t ws_size,
                              hipStream_t stream)
{
    const float* x     = (const float*)d_in[0];
    const float* t     = (const float*)d_in[1];
    const int*   ldi   = (const int*)  d_in[2];
    const float* ldv   = (const float*)d_in[3];
    const int*   lui   = (const int*)  d_in[4];
    const float* luv   = (const float*)d_in[5];
    const float* W1    = (const float*)d_in[6];
    const float* W2    = (const float*)d_in[7];
    const float* t_w1  = (const float*)d_in[8];
    const float* t_b1  = (const float*)d_in[9];
    const float* t_w2  = (const float*)d_in[10];
    const float* t_b2  = (const float*)d_in[11];
    const float* map_w = (const float*)d_in[12];
    const float* map_b = (const float*)d_in[13];
    const float* o_w1  = (const float*)d_in[14];
    const float* o_b1  = (const float*)d_in[15];
    const float* o_w2  = (const float*)d_in[16];
    const float* o_b2  = (const float*)d_in[17];
    float* out = (float*)d_out;
    float* ws  = (float*)d_ws;

    float* xT = ws + OFF_XT;
    float* dd = ws + OFF_DD;
    float* uu = ws + OFF_UU;
    float* hb = ws + OFF_HB;
    float* hc = ws + OFF_HC;
    float* y  = ws + OFF_Y;

    k_prep<<<258, 256, 0, stream>>>(x, t, W1, W2, t_w1, t_b1, t_w2, t_b2,
                                    map_b, o_b2, ws, out);
    k_scatter<<<2 * E * 8 / 256, 256, 0, stream>>>(ldi, ldv, lui, luv, xT, xT, dd, uu);
    k_mid<<<256, 256, 0, stream>>>(ws);
    k_scatter<<<2 * E * 8 / 256, 256, 0, stream>>>(ldi, ldv, lui, luv, hb, hc, y, y);
    k_map<<<64, 256, 0, stream>>>(map_w, ws);
    k_mlp<<<8, 256, 0, stream>>>(o_w1, o_b1, ws);
    k_out<<<dim3(32, 4), 256, 0, stream>>>(o_w2, ws, out);
}

// Round 2
// 91.117 us; speedup vs baseline: 1.1356x; 1.1356x over previous
//
#include <hip/hip_runtime.h>
#include <math.h>

#define D 8192
#define B 8
#define E 131072
#define HID 256
#define TDIM 128

// ws layout (float offsets)
#define OFF_XT 0
#define OFF_DD 65536
#define OFF_UU 131072
#define OFF_HB 196608
#define OFF_HC 262144
#define OFF_Y  327680
#define OFF_G  393216
#define OFF_S  395264
#define OFF_SC 397312

// transpose x -> xT[n*8+b], zero dd/uu, init out with o_b2
__global__ void k_prep_main(const float* __restrict__ x, const float* __restrict__ o_b2,
                            float* __restrict__ ws, float* __restrict__ out)
{
    int idx = blockIdx.x * 256 + threadIdx.x;     // 0..65535
    int b = idx & 7, n = idx >> 3;
    ws[OFF_XT + idx] = x[b * D + n];
    ws[OFF_DD + idx] = 0.f;
    ws[OFF_UU + idx] = 0.f;
    out[idx] = o_b2[idx & (D - 1)];               // idx = b*D + n
}

// blocks 0..7: per-batch time-embedding MLP -> g = map_b + t_out
// block 8: 9 collapsed scalars sc[j*3+k] = sum_i W1[0,i,k]*W2[i,0,j]
__global__ void k_tmlp(const float* __restrict__ t,
                       const float* __restrict__ W1, const float* __restrict__ W2,
                       const float* __restrict__ t_w1, const float* __restrict__ t_b1,
                       const float* __restrict__ t_w2, const float* __restrict__ t_b2,
                       const float* __restrict__ map_b, float* __restrict__ ws)
{
    const int blk = blockIdx.x, tid = threadIdx.x;
    if (blk == 8) {
        __shared__ float red[256];
        float w1k[3], w2j[3];
        #pragma unroll
        for (int k = 0; k < 3; k++) w1k[k] = W1[tid * 3 + k];
        #pragma unroll
        for (int j = 0; j < 3; j++) w2j[j] = W2[tid * 3 + j];
        float* sc = ws + OFF_SC;
        for (int j = 0; j < 3; j++)
            for (int k = 0; k < 3; k++) {
                red[tid] = w1k[k] * w2j[j];
                __syncthreads();
                for (int off = 128; off > 0; off >>= 1) {
                    if (tid < off) red[tid] += red[tid + off];
                    __syncthreads();
                }
                if (tid == 0) sc[j * 3 + k] = red[0];
                __syncthreads();
            }
        return;
    }
    const int b = blk;
    __shared__ float emb[TDIM];
    __shared__ float h1[HID];
    float* g = ws + OFF_G;
    float tb = t[b];
    if (tid < TDIM) {
        int j = tid & 63;
        float freq = expf(-0.14391156831212787f * (float)j); // ln(10000)/64
        float a = tb * freq;
        emb[tid] = (tid < 64) ? cosf(a) : sinf(a);
    }
    __syncthreads();
    float z = t_b1[tid];
    #pragma unroll 4
    for (int i = 0; i < TDIM; i++) z += emb[i] * t_w1[i * HID + tid];
    h1[tid] = z / (1.f + expf(-z));
    __syncthreads();
    float z2 = t_b2[tid];
    #pragma unroll 4
    for (int i = 0; i < HID; i++) z2 += h1[i] * t_w2[i * HID + tid];
    g[b * HID + tid] = map_b[tid] + z2;
}

// COO scatter: dst[row,b] += v * src[col,b] for both Laplacians.
__global__ void k_scatter(const int* __restrict__ ldi, const float* __restrict__ ldv,
                          const int* __restrict__ lui, const float* __restrict__ luv,
                          const float* __restrict__ src_d, const float* __restrict__ src_u,
                          float* __restrict__ dst_d, float* __restrict__ dst_u)
{
    int gtid = blockIdx.x * 256 + threadIdx.x;    // 0 .. 2*E*8-1
    int b = gtid & 7;
    int e = gtid >> 3;
    const int* idx; const float* val; const float* src; float* dst;
    if (e < E) { idx = ldi; val = ldv; src = src_d; dst = dst_d; }
    else       { e -= E; idx = lui; val = luv; src = src_u; dst = dst_u; }
    int row = idx[e];
    int col = idx[E + e];
    float v = val[e];
    atomicAdd(&dst[row * 8 + b], v * src[col * 8 + b]);
}

__global__ void k_mid(float* __restrict__ ws)
{
    int idx = blockIdx.x * 256 + threadIdx.x;     // 0..65535
    const float* sc = ws + OFF_SC;
    float xv = ws[OFF_XT + idx];
    float dv = ws[OFF_DD + idx];
    float uv = ws[OFF_UU + idx];
    ws[OFF_Y  + idx] = sc[0] * xv + sc[1] * dv + sc[2] * uv;
    ws[OFF_HB + idx] = sc[3] * xv + sc[4] * dv + sc[5] * uv;
    ws[OFF_HC + idx] = sc[6] * xv + sc[7] * dv + sc[8] * uv;
}

// g[b,j] += sum_n y[n,b] * map_w[n,j]   (64 blocks x 128 rows each)
__global__ void k_map(const float* __restrict__ map_w, float* __restrict__ ws)
{
    __shared__ float ysl[128 * 8];
    int blk = blockIdx.x, tid = threadIdx.x;
    const float* y = ws + OFF_Y;
    float* g = ws + OFF_G;
    int base = blk * 128 * 8;
    for (int i = tid; i < 1024; i += 256) ysl[i] = y[base + i];
    __syncthreads();
    float acc[8] = {0.f, 0.f, 0.f, 0.f, 0.f, 0.f, 0.f, 0.f};
    int nbase = blk * 128;
    for (int r = 0; r < 128; r++) {
        float w = map_w[(nbase + r) * HID + tid];
        #pragma unroll
        for (int b = 0; b < 8; b++) acc[b] += ysl[r * 8 + b] * w;
    }
    #pragma unroll
    for (int b = 0; b < 8; b++) atomicAdd(&g[b * HID + tid], acc[b]);
}

// s[b,j] = silu(sum_i g[b,i]*o_w1[i,j] + o_b1[j])   (8 blocks, one per batch)
__global__ void k_mlp(const float* __restrict__ o_w1, const float* __restrict__ o_b1,
                      float* __restrict__ ws)
{
    __shared__ float gs[HID];
    int b = blockIdx.x, tid = threadIdx.x;
    const float* g = ws + OFF_G;
    float* s = ws + OFF_S;
    gs[tid] = g[b * HID + tid];
    __syncthreads();
    float z = o_b1[tid];
    #pragma unroll 4
    for (int i = 0; i < HID; i++) z += gs[i] * o_w1[i * HID + tid];
    s[b * HID + tid] = z / (1.f + expf(-z));
}

// out[b,n] += sum_j s[b,j]*o_w2[j,n]   (grid 32 n-chunks x 4 j-chunks)
__global__ void k_out(const float* __restrict__ o_w2, const float* __restrict__ ws,
                      float* __restrict__ out)
{
    __shared__ float ssl[8 * 64];
    int nc = blockIdx.x, jc = blockIdx.y, tid = threadIdx.x;
    const float* s = ws + OFF_S;
    for (int i = tid; i < 512; i += 256) {
        int b = i >> 6, jj = i & 63;
        ssl[i] = s[b * HID + jc * 64 + jj];
    }
    __syncthreads();
    int n = nc * 256 + tid;
    float acc[8] = {0.f, 0.f, 0.f, 0.f, 0.f, 0.f, 0.f, 0.f};
    for (int jj = 0; jj < 64; jj++) {
        int j = jc * 64 + jj;
        float w = o_w2[j * D + n];
        #pragma unroll
        for (int b = 0; b < 8; b++) acc[b] += ssl[b * 64 + jj] * w;
    }
    #pragma unroll
    for (int b = 0; b < 8; b++) atomicAdd(&out[b * D + n], acc[b]);
}

extern "C" void kernel_launch(void* const* d_in, const int* in_sizes, int n_in,
                              void* d_out, int out_size, void* d_ws, size_t ws_size,
                              hipStream_t stream)
{
    const float* x     = (const float*)d_in[0];
    const float* t     = (const float*)d_in[1];
    const int*   ldi   = (const int*)  d_in[2];
    const float* ldv   = (const float*)d_in[3];
    const int*   lui   = (const int*)  d_in[4];
    const float* luv   = (const float*)d_in[5];
    const float* W1    = (const float*)d_in[6];
    const float* W2    = (const float*)d_in[7];
    const float* t_w1  = (const float*)d_in[8];
    const float* t_b1  = (const float*)d_in[9];
    const float* t_w2  = (const float*)d_in[10];
    const float* t_b2  = (const float*)d_in[11];
    const float* map_w = (const float*)d_in[12];
    const float* map_b = (const float*)d_in[13];
    const float* o_w1  = (const float*)d_in[14];
    const float* o_b1  = (const float*)d_in[15];
    const float* o_w2  = (const float*)d_in[16];
    const float* o_b2  = (const float*)d_in[17];
    float* out = (float*)d_out;
    float* ws  = (float*)d_ws;

    float* xT = ws + OFF_XT;
    float* dd = ws + OFF_DD;
    float* uu = ws + OFF_UU;
    float* hb = ws + OFF_HB;
    float* hc = ws + OFF_HC;
    float* y  = ws + OFF_Y;

    k_prep_main<<<256, 256, 0, stream>>>(x, o_b2, ws, out);
    k_tmlp<<<9, 256, 0, stream>>>(t, W1, W2, t_w1, t_b1, t_w2, t_b2, map_b, ws);
    k_scatter<<<2 * E * 8 / 256, 256, 0, stream>>>(ldi, ldv, lui, luv, xT, xT, dd, uu);
    k_mid<<<256, 256, 0, stream>>>(ws);
    k_scatter<<<2 * E * 8 / 256, 256, 0, stream>>>(ldi, ldv, lui, luv, hb, hc, y, y);
    k_map<<<64, 256, 0, stream>>>(map_w, ws);
    k_mlp<<<8, 256, 0, stream>>>(o_w1, o_b1, ws);
    k_out<<<dim3(32, 4), 256, 0, stream>>>(o_w2, ws, out);
}

// Round 3
// 72.749 us; speedup vs baseline: 1.4223x; 1.2525x over previous
//
#include <hip/hip_runtime.h>
#include <math.h>

#define D 8192
#define B 8
#define E 131072
#define HID 256
#define TDIM 128

// ws layout (float offsets)
#define OFF_XT 0
#define OFF_DD 65536
#define OFF_UU 131072
#define OFF_HB 196608
#define OFF_HC 262144
#define OFF_Y  327680
#define OFF_G  393216
#define OFF_S  395264
#define OFF_SC 397312

// blocks 0..63   : prep (transpose x -> xT, zero dd/uu, out = o_b2)
// blocks 64..71  : per-batch time-embedding MLP -> g = map_b + t_out
// block  72      : 9 collapsed scalars sc[j*3+k] = sum_i W1[0,i,k]*W2[i,0,j]
__global__ __launch_bounds__(1024) void k_front(
        const float* __restrict__ x, const float* __restrict__ t,
        const float* __restrict__ W1, const float* __restrict__ W2,
        const float* __restrict__ t_w1, const float* __restrict__ t_b1,
        const float* __restrict__ t_w2, const float* __restrict__ t_b2,
        const float* __restrict__ map_b, const float* __restrict__ o_b2,
        float* __restrict__ ws, float* __restrict__ out)
{
    const int blk = blockIdx.x, tid = threadIdx.x;
    if (blk < 64) {
        int idx = blk * 1024 + tid;               // 0..65535
        int b = idx & 7, n = idx >> 3;
        ws[OFF_XT + idx] = x[b * D + n];
        ws[OFF_DD + idx] = 0.f;
        ws[OFF_UU + idx] = 0.f;
        out[idx] = o_b2[idx & (D - 1)];           // idx = b*D + n
        return;
    }
    if (blk < 72) {
        const int b = blk - 64;
        __shared__ float emb[TDIM];
        __shared__ float h1[HID];
        __shared__ float part[4][HID];
        float tb = t[b];
        if (tid < TDIM) {
            int j = tid & 63;
            float freq = expf(-0.14391156831212787f * (float)j); // ln(10000)/64
            float a = tb * freq;
            emb[tid] = (tid < 64) ? cosf(a) : sinf(a);
        }
        __syncthreads();
        const int j = tid & 255, ic = tid >> 8;   // ic in 0..3
        float z = 0.f;
        #pragma unroll 8
        for (int i = ic * 32; i < ic * 32 + 32; i++) z += emb[i] * t_w1[i * HID + j];
        part[ic][j] = z;
        __syncthreads();
        if (tid < HID) {
            float zz = t_b1[tid] + part[0][tid] + part[1][tid] + part[2][tid] + part[3][tid];
            h1[tid] = zz / (1.f + expf(-zz));
        }
        __syncthreads();
        float z2 = 0.f;
        #pragma unroll 8
        for (int i = ic * 64; i < ic * 64 + 64; i++) z2 += h1[i] * t_w2[i * HID + j];
        part[ic][j] = z2;
        __syncthreads();
        if (tid < HID) {
            float zz = t_b2[tid] + part[0][tid] + part[1][tid] + part[2][tid] + part[3][tid];
            (ws + OFF_G)[b * HID + tid] = map_b[tid] + zz;
        }
        return;
    }
    // block 72: 9 scalars via per-wave shuffle reduction (waves 0..8)
    {
        int w = tid >> 6, lane = tid & 63;
        if (w < 9) {
            int jj = w / 3, k = w % 3;
            float acc = 0.f;
            #pragma unroll
            for (int q = 0; q < 4; q++) {
                int i = lane + 64 * q;
                acc += W1[i * 3 + k] * W2[i * 3 + jj];
            }
            #pragma unroll
            for (int off = 32; off > 0; off >>= 1) acc += __shfl_down(acc, off, 64);
            if (lane == 0) (ws + OFF_SC)[jj * 3 + k] = acc;
        }
    }
}

// COO scatter: dst[row,b] += v * src[col,b] for both Laplacians.
__global__ void k_scatter(const int* __restrict__ ldi, const float* __restrict__ ldv,
                          const int* __restrict__ lui, const float* __restrict__ luv,
                          const float* __restrict__ src_d, const float* __restrict__ src_u,
                          float* __restrict__ dst_d, float* __restrict__ dst_u)
{
    int gtid = blockIdx.x * 256 + threadIdx.x;    // 0 .. 2*E*8-1
    int b = gtid & 7;
    int e = gtid >> 3;
    const int* idx; const float* val; const float* src; float* dst;
    if (e < E) { idx = ldi; val = ldv; src = src_d; dst = dst_d; }
    else       { e -= E; idx = lui; val = luv; src = src_u; dst = dst_u; }
    int row = idx[e];
    int col = idx[E + e];
    float v = val[e];
    atomicAdd(&dst[row * 8 + b], v * src[col * 8 + b]);
}

__global__ void k_mid(float* __restrict__ ws)
{
    int idx = blockIdx.x * 256 + threadIdx.x;     // 0..65535
    const float* sc = ws + OFF_SC;
    float xv = ws[OFF_XT + idx];
    float dv = ws[OFF_DD + idx];
    float uv = ws[OFF_UU + idx];
    ws[OFF_Y  + idx] = sc[0] * xv + sc[1] * dv + sc[2] * uv;
    ws[OFF_HB + idx] = sc[3] * xv + sc[4] * dv + sc[5] * uv;
    ws[OFF_HC + idx] = sc[6] * xv + sc[7] * dv + sc[8] * uv;
}

// g[b,j] += sum_n y[n,b] * map_w[n,j]   (64 blocks x 128 rows each)
__global__ void k_map(const float* __restrict__ map_w, float* __restrict__ ws)
{
    __shared__ float ysl[128 * 8];
    int blk = blockIdx.x, tid = threadIdx.x;
    const float* y = ws + OFF_Y;
    float* g = ws + OFF_G;
    int base = blk * 128 * 8;
    for (int i = tid; i < 1024; i += 256) ysl[i] = y[base + i];
    __syncthreads();
    float acc[8] = {0.f, 0.f, 0.f, 0.f, 0.f, 0.f, 0.f, 0.f};
    int nbase = blk * 128;
    for (int r = 0; r < 128; r++) {
        float w = map_w[(nbase + r) * HID + tid];
        #pragma unroll
        for (int b = 0; b < 8; b++) acc[b] += ysl[r * 8 + b] * w;
    }
    #pragma unroll
    for (int b = 0; b < 8; b++) atomicAdd(&g[b * HID + tid], acc[b]);
}

// s[b,j] = silu(sum_i g[b,i]*o_w1[i,j] + o_b1[j])   (8 blocks, one per batch)
__global__ void k_mlp(const float* __restrict__ o_w1, const float* __restrict__ o_b1,
                      float* __restrict__ ws)
{
    __shared__ float gs[HID];
    int b = blockIdx.x, tid = threadIdx.x;
    const float* g = ws + OFF_G;
    float* s = ws + OFF_S;
    gs[tid] = g[b * HID + tid];
    __syncthreads();
    float z = o_b1[tid];
    #pragma unroll 4
    for (int i = 0; i < HID; i++) z += gs[i] * o_w1[i * HID + tid];
    s[b * HID + tid] = z / (1.f + expf(-z));
}

// out[b,n] += sum_j s[b,j]*o_w2[j,n]   (grid 32 n-chunks x 4 j-chunks)
__global__ void k_out(const float* __restrict__ o_w2, const float* __restrict__ ws,
                      float* __restrict__ out)
{
    __shared__ float ssl[8 * 64];
    int nc = blockIdx.x, jc = blockIdx.y, tid = threadIdx.x;
    const float* s = ws + OFF_S;
    for (int i = tid; i < 512; i += 256) {
        int b = i >> 6, jj = i & 63;
        ssl[i] = s[b * HID + jc * 64 + jj];
    }
    __syncthreads();
    int n = nc * 256 + tid;
    float acc[8] = {0.f, 0.f, 0.f, 0.f, 0.f, 0.f, 0.f, 0.f};
    for (int jj = 0; jj < 64; jj++) {
        int j = jc * 64 + jj;
        float w = o_w2[j * D + n];
        #pragma unroll
        for (int b = 0; b < 8; b++) acc[b] += ssl[b * 64 + jj] * w;
    }
    #pragma unroll
    for (int b = 0; b < 8; b++) atomicAdd(&out[b * D + n], acc[b]);
}

extern "C" void kernel_launch(void* const* d_in, const int* in_sizes, int n_in,
                              void* d_out, int out_size, void* d_ws, size_t ws_size,
                              hipStream_t stream)
{
    const float* x     = (const float*)d_in[0];
    const float* t     = (const float*)d_in[1];
    const int*   ldi   = (const int*)  d_in[2];
    const float* ldv   = (const float*)d_in[3];
    const int*   lui   = (const int*)  d_in[4];
    const float* luv   = (const float*)d_in[5];
    const float* W1    = (const float*)d_in[6];
    const float* W2    = (const float*)d_in[7];
    const float* t_w1  = (const float*)d_in[8];
    const float* t_b1  = (const float*)d_in[9];
    const float* t_w2  = (const float*)d_in[10];
    const float* t_b2  = (const float*)d_in[11];
    const float* map_w = (const float*)d_in[12];
    const float* map_b = (const float*)d_in[13];
    const float* o_w1  = (const float*)d_in[14];
    const float* o_b1  = (const float*)d_in[15];
    const float* o_w2  = (const float*)d_in[16];
    const float* o_b2  = (const float*)d_in[17];
    float* out = (float*)d_out;
    float* ws  = (float*)d_ws;

    float* xT = ws + OFF_XT;
    float* dd = ws + OFF_DD;
    float* uu = ws + OFF_UU;
    float* hb = ws + OFF_HB;
    float* hc = ws + OFF_HC;
    float* y  = ws + OFF_Y;

    k_front<<<73, 1024, 0, stream>>>(x, t, W1, W2, t_w1, t_b1, t_w2, t_b2,
                                     map_b, o_b2, ws, out);
    k_scatter<<<2 * E * 8 / 256, 256, 0, stream>>>(ldi, ldv, lui, luv, xT, xT, dd, uu);
    k_mid<<<256, 256, 0, stream>>>(ws);
    k_scatter<<<2 * E * 8 / 256, 256, 0, stream>>>(ldi, ldv, lui, luv, hb, hc, y, y);
    k_map<<<64, 256, 0, stream>>>(map_w, ws);
    k_mlp<<<8, 256, 0, stream>>>(o_w1, o_b1, ws);
    k_out<<<dim3(32, 4), 256, 0, stream>>>(o_w2, ws, out);
}

// Round 4
// 62.777 us; speedup vs baseline: 1.6483x; 1.1589x over previous
//
#include <hip/hip_runtime.h>
#include <math.h>

#define D 8192
#define B 8
#define E 131072
#define HID 256
#define TDIM 128

// ws layout (float offsets)
#define OFF_XT 0
#define OFF_DD 65536
#define OFF_UU 131072
#define OFF_Y  196608
#define OFF_G  262144
#define OFF_S  264192
#define OFF_SC 266240

// blocks 0..63   : prep (transpose x -> xT, zero dd/uu/y, out = o_b2)
// blocks 64..71  : per-batch time-embedding MLP -> g = map_b + t_out
// block  72      : 9 collapsed scalars sc[j*3+k] = sum_i W1[0,i,k]*W2[i,0,j]
__global__ __launch_bounds__(1024) void k_front(
        const float* __restrict__ x, const float* __restrict__ t,
        const float* __restrict__ W1, const float* __restrict__ W2,
        const float* __restrict__ t_w1, const float* __restrict__ t_b1,
        const float* __restrict__ t_w2, const float* __restrict__ t_b2,
        const float* __restrict__ map_b, const float* __restrict__ o_b2,
        float* __restrict__ ws, float* __restrict__ out)
{
    const int blk = blockIdx.x, tid = threadIdx.x;
    if (blk < 64) {
        int idx = blk * 1024 + tid;               // 0..65535
        int b = idx & 7, n = idx >> 3;
        ws[OFF_XT + idx] = x[b * D + n];
        ws[OFF_DD + idx] = 0.f;
        ws[OFF_UU + idx] = 0.f;
        ws[OFF_Y  + idx] = 0.f;
        out[idx] = o_b2[idx & (D - 1)];           // idx = b*D + n
        return;
    }
    if (blk < 72) {
        const int b = blk - 64;
        __shared__ float emb[TDIM];
        __shared__ float h1[HID];
        __shared__ float part[4][HID];
        float tb = t[b];
        if (tid < TDIM) {
            int j = tid & 63;
            float freq = expf(-0.14391156831212787f * (float)j); // ln(10000)/64
            float a = tb * freq;
            emb[tid] = (tid < 64) ? cosf(a) : sinf(a);
        }
        __syncthreads();
        const int j = tid & 255, ic = tid >> 8;   // ic in 0..3
        float z = 0.f;
        #pragma unroll 8
        for (int i = ic * 32; i < ic * 32 + 32; i++) z += emb[i] * t_w1[i * HID + j];
        part[ic][j] = z;
        __syncthreads();
        if (tid < HID) {
            float zz = t_b1[tid] + part[0][tid] + part[1][tid] + part[2][tid] + part[3][tid];
            h1[tid] = zz / (1.f + expf(-zz));
        }
        __syncthreads();
        float z2 = 0.f;
        #pragma unroll 8
        for (int i = ic * 64; i < ic * 64 + 64; i++) z2 += h1[i] * t_w2[i * HID + j];
        part[ic][j] = z2;
        __syncthreads();
        if (tid < HID) {
            float zz = t_b2[tid] + part[0][tid] + part[1][tid] + part[2][tid] + part[3][tid];
            (ws + OFF_G)[b * HID + tid] = map_b[tid] + zz;
        }
        return;
    }
    // block 72: 9 scalars via per-wave shuffle reduction (waves 0..8)
    {
        int w = tid >> 6, lane = tid & 63;
        if (w < 9) {
            int jj = w / 3, k = w % 3;
            float acc = 0.f;
            #pragma unroll
            for (int q = 0; q < 4; q++) {
                int i = lane + 64 * q;
                acc += W1[i * 3 + k] * W2[i * 3 + jj];
            }
            #pragma unroll
            for (int off = 32; off > 0; off >>= 1) acc += __shfl_down(acc, off, 64);
            if (lane == 0) (ws + OFF_SC)[jj * 3 + k] = acc;
        }
    }
}

// pass 1: dd[row,b] += v * xT[col,b] ; uu[row,b] += v * xT[col,b]
__global__ void k_scat1(const int* __restrict__ ldi, const float* __restrict__ ldv,
                        const int* __restrict__ lui, const float* __restrict__ luv,
                        float* __restrict__ ws)
{
    int gtid = blockIdx.x * 256 + threadIdx.x;    // 0 .. 2*E*8-1
    int b = gtid & 7;
    int e = gtid >> 3;
    const int* idx; const float* val; float* dst;
    if (e < E) { idx = ldi; val = ldv; dst = ws + OFF_DD; }
    else       { e -= E; idx = lui; val = luv; dst = ws + OFF_UU; }
    int row = idx[e];
    int col = idx[E + e];
    float v = val[e];
    atomicAdd(&dst[row * 8 + b], v * ws[OFF_XT + col * 8 + b]);
}

// pass 2: y[row,b] += v * h(col,b)  with h computed on the fly:
//   L_d edges: h = sc3*x + sc4*d + sc5*u ;  L_u edges: h = sc6*x + sc7*d + sc8*u
__global__ void k_scat2(const int* __restrict__ ldi, const float* __restrict__ ldv,
                        const int* __restrict__ lui, const float* __restrict__ luv,
                        float* __restrict__ ws)
{
    int gtid = blockIdx.x * 256 + threadIdx.x;    // 0 .. 2*E*8-1
    int b = gtid & 7;
    int e = gtid >> 3;
    const float* sc = ws + OFF_SC;
    const int* idx; const float* val; float c0, c1, c2;
    if (e < E) { idx = ldi; val = ldv; c0 = sc[3]; c1 = sc[4]; c2 = sc[5]; }
    else       { e -= E; idx = lui; val = luv; c0 = sc[6]; c1 = sc[7]; c2 = sc[8]; }
    int row = idx[e];
    int col = idx[E + e];
    float v = val[e];
    int ci = col * 8 + b;
    float h = c0 * ws[OFF_XT + ci] + c1 * ws[OFF_DD + ci] + c2 * ws[OFF_UU + ci];
    atomicAdd(&ws[OFF_Y + row * 8 + b], v * h);
}

// g[b,j] += sum_n yfull[n,b] * map_w[n,j], yfull = a0*x + a1*d + a2*u + y_atomic
// 256 blocks x 32 rows each
__global__ void k_map(const float* __restrict__ map_w, float* __restrict__ ws)
{
    __shared__ float yf[32 * 8];
    int blk = blockIdx.x, tid = threadIdx.x;
    const float* sc = ws + OFF_SC;
    float* g = ws + OFF_G;
    int base = blk * 32 * 8;
    {
        float a0 = sc[0], a1 = sc[1], a2 = sc[2];
        int i = base + tid;                       // tid covers all 256 elems
        yf[tid] = a0 * ws[OFF_XT + i] + a1 * ws[OFF_DD + i] + a2 * ws[OFF_UU + i]
                + ws[OFF_Y + i];
    }
    __syncthreads();
    float acc[8] = {0.f, 0.f, 0.f, 0.f, 0.f, 0.f, 0.f, 0.f};
    int nbase = blk * 32;
    #pragma unroll 4
    for (int r = 0; r < 32; r++) {
        float w = map_w[(nbase + r) * HID + tid];
        #pragma unroll
        for (int b = 0; b < 8; b++) acc[b] += yf[r * 8 + b] * w;
    }
    #pragma unroll
    for (int b = 0; b < 8; b++) atomicAdd(&g[b * HID + tid], acc[b]);
}

// s[b,j] = silu(sum_i g[b,i]*o_w1[i,j] + o_b1[j])  (8 blocks x 1024 thr, 4-way split)
__global__ __launch_bounds__(1024) void k_mlp(const float* __restrict__ o_w1,
                                              const float* __restrict__ o_b1,
                                              float* __restrict__ ws)
{
    __shared__ float gs[HID];
    __shared__ float part[4][HID];
    int b = blockIdx.x, tid = threadIdx.x;
    if (tid < HID) gs[tid] = (ws + OFF_G)[b * HID + tid];
    __syncthreads();
    int j = tid & 255, ic = tid >> 8;
    float z = 0.f;
    #pragma unroll 8
    for (int i = ic * 64; i < ic * 64 + 64; i++) z += gs[i] * o_w1[i * HID + j];
    part[ic][j] = z;
    __syncthreads();
    if (tid < HID) {
        float zz = o_b1[tid] + part[0][tid] + part[1][tid] + part[2][tid] + part[3][tid];
        (ws + OFF_S)[b * HID + tid] = zz / (1.f + expf(-zz));
    }
}

// out[b,n] += sum_j s[b,j]*o_w2[j,n]   (grid 32 n-chunks x 4 j-chunks)
__global__ void k_out(const float* __restrict__ o_w2, const float* __restrict__ ws,
                      float* __restrict__ out)
{
    __shared__ float ssl[8 * 64];
    int nc = blockIdx.x, jc = blockIdx.y, tid = threadIdx.x;
    const float* s = ws + OFF_S;
    for (int i = tid; i < 512; i += 256) {
        int b = i >> 6, jj = i & 63;
        ssl[i] = s[b * HID + jc * 64 + jj];
    }
    __syncthreads();
    int n = nc * 256 + tid;
    float acc[8] = {0.f, 0.f, 0.f, 0.f, 0.f, 0.f, 0.f, 0.f};
    #pragma unroll 4
    for (int jj = 0; jj < 64; jj++) {
        int j = jc * 64 + jj;
        float w = o_w2[j * D + n];
        #pragma unroll
        for (int b = 0; b < 8; b++) acc[b] += ssl[b * 64 + jj] * w;
    }
    #pragma unroll
    for (int b = 0; b < 8; b++) atomicAdd(&out[b * D + n], acc[b]);
}

extern "C" void kernel_launch(void* const* d_in, const int* in_sizes, int n_in,
                              void* d_out, int out_size, void* d_ws, size_t ws_size,
                              hipStream_t stream)
{
    const float* x     = (const float*)d_in[0];
    const float* t     = (const float*)d_in[1];
    const int*   ldi   = (const int*)  d_in[2];
    const float* ldv   = (const float*)d_in[3];
    const int*   lui   = (const int*)  d_in[4];
    const float* luv   = (const float*)d_in[5];
    const float* W1    = (const float*)d_in[6];
    const float* W2    = (const float*)d_in[7];
    const float* t_w1  = (const float*)d_in[8];
    const float* t_b1  = (const float*)d_in[9];
    const float* t_w2  = (const float*)d_in[10];
    const float* t_b2  = (const float*)d_in[11];
    const float* map_w = (const float*)d_in[12];
    const float* map_b = (const float*)d_in[13];
    const float* o_w1  = (const float*)d_in[14];
    const float* o_b1  = (const float*)d_in[15];
    const float* o_w2  = (const float*)d_in[16];
    const float* o_b2  = (const float*)d_in[17];
    float* out = (float*)d_out;
    float* ws  = (float*)d_ws;

    k_front<<<73, 1024, 0, stream>>>(x, t, W1, W2, t_w1, t_b1, t_w2, t_b2,
                                     map_b, o_b2, ws, out);
    k_scat1<<<2 * E * 8 / 256, 256, 0, stream>>>(ldi, ldv, lui, luv, ws);
    k_scat2<<<2 * E * 8 / 256, 256, 0, stream>>>(ldi, ldv, lui, luv, ws);
    k_map<<<256, 256, 0, stream>>>(map_w, ws);
    k_mlp<<<8, 1024, 0, stream>>>(o_w1, o_b1, ws);
    k_out<<<dim3(32, 4), 256, 0, stream>>>(o_w2, ws, out);
}